// Round 1
// baseline (697.063 us; speedup 1.0000x reference)
//
#include <hip/hip_runtime.h>
#include <hip/hip_bf16.h>

typedef unsigned short ushort_t;
typedef __attribute__((ext_vector_type(8))) short short8;
typedef __attribute__((ext_vector_type(4))) float f32x4;
typedef __attribute__((ext_vector_type(4))) unsigned int uint4v;

#define NQ      2048
#define ND      512
#define NDB     100000
#define TOPK    10
#define NCHUNK  50
#define CHUNK_N 2048                  // 16 tiles * 128
#define NPAD    (NCHUNK * CHUNK_N)    // 102400
#define QTILES  (NQ / 128)            // 16
#define NTILES  (CHUNK_N / 128)       // 16
#define LDA     72                    // 64 + 8 bf16 pad (keeps 16B align, breaks bank stride)

// ---------- fp32 -> bf16 (round to nearest even) ----------
static __device__ inline ushort_t f2bf(float x) {
    unsigned u = __float_as_uint(x);
    unsigned r = (u + 0x7FFFu + ((u >> 16) & 1u)) >> 16;
    return (ushort_t)r;
}

// ---------- row L2-normalize, fp32 -> bf16, one wave per row ----------
__global__ void normalize_rows(const float* __restrict__ in, ushort_t* __restrict__ out, int nrows) {
    int row  = blockIdx.x * 4 + (threadIdx.x >> 6);
    int lane = threadIdx.x & 63;
    if (row >= nrows) return;
    const float4* src = reinterpret_cast<const float4*>(in + (size_t)row * ND);
    float4 v0 = src[lane * 2];
    float4 v1 = src[lane * 2 + 1];
    float s = v0.x*v0.x + v0.y*v0.y + v0.z*v0.z + v0.w*v0.w
            + v1.x*v1.x + v1.y*v1.y + v1.z*v1.z + v1.w*v1.w;
    #pragma unroll
    for (int off = 32; off; off >>= 1) s += __shfl_xor(s, off, 64);
    float r = rsqrtf(s);
    ushort_t o[8];
    o[0] = f2bf(v0.x * r); o[1] = f2bf(v0.y * r); o[2] = f2bf(v0.z * r); o[3] = f2bf(v0.w * r);
    o[4] = f2bf(v1.x * r); o[5] = f2bf(v1.y * r); o[6] = f2bf(v1.z * r); o[7] = f2bf(v1.w * r);
    uint4v pk;
    pk[0] = (unsigned)o[0] | ((unsigned)o[1] << 16);
    pk[1] = (unsigned)o[2] | ((unsigned)o[3] << 16);
    pk[2] = (unsigned)o[4] | ((unsigned)o[5] << 16);
    pk[3] = (unsigned)o[6] | ((unsigned)o[7] << 16);
    *reinterpret_cast<uint4v*>(out + (size_t)row * ND + lane * 8) = pk;
}

__device__ inline void topk_insert(float (&top)[TOPK], float x) {
    #pragma unroll
    for (int i = 0; i < TOPK; ++i) {
        float mx = fmaxf(top[i], x);
        x = fminf(top[i], x);
        top[i] = mx;
    }
}

// ---------- fused GEMM + per-chunk top-10 ----------
// grid: NCHUNK * QTILES blocks, 256 threads (4 waves, 2x2 wave grid, 64x64 per wave)
__global__ __launch_bounds__(256)
void knn_chunk(const ushort_t* __restrict__ qb, const ushort_t* __restrict__ dbb,
               float* __restrict__ partial) {
    const int bid = blockIdx.x;
    const int qt = bid & (QTILES - 1);
    const int nc = bid >> 4;           // QTILES == 16
    const int t = threadIdx.x, lane = t & 63, wv = t >> 6;
    const int wr = wv >> 1, wc = wv & 1;

    __shared__ __align__(16) ushort_t smem[2 * 128 * LDA];
    ushort_t* As = smem;
    ushort_t* Bs = smem + 128 * LDA;
    float* Ss = (float*)smem;          // overlay: scores [128][72]
    float* Ms = (float*)smem;          // overlay: merge  [128][20]

    float top[TOPK];
    #pragma unroll
    for (int i = 0; i < TOPK; ++i) top[i] = -1e30f;

    const int qbase = qt * 128;
    const size_t nchunkbase = (size_t)nc * CHUNK_N;

    for (int nt = 0; nt < NTILES; ++nt) {
        const size_t nbase = nchunkbase + nt * 128;
        f32x4 acc[4][4];
        #pragma unroll
        for (int a = 0; a < 4; ++a)
            #pragma unroll
            for (int b = 0; b < 4; ++b)
                acc[a][b] = (f32x4){0.f, 0.f, 0.f, 0.f};

        #pragma unroll 1
        for (int ks = 0; ks < 8; ++ks) {
            const int kbase = ks * 64;
            __syncthreads();   // protect previous frag reads / score scan
            #pragma unroll
            for (int i = 0; i < 4; ++i) {
                int cid = t + i * 256;           // 0..1023 16B-chunks
                int row = cid >> 3;
                int co  = (cid & 7) * 8;
                uint4v va = *reinterpret_cast<const uint4v*>(qb  + ((size_t)(qbase + row)) * ND + kbase + co);
                *reinterpret_cast<uint4v*>(As + row * LDA + co) = va;
                uint4v vb = *reinterpret_cast<const uint4v*>(dbb + (nbase + row) * ND + kbase + co);
                *reinterpret_cast<uint4v*>(Bs + row * LDA + co) = vb;
            }
            __syncthreads();
            #pragma unroll
            for (int ksub = 0; ksub < 2; ++ksub) {
                const int colo = ksub * 32 + (lane >> 4) * 8;
                short8 af[4], bf[4];
                #pragma unroll
                for (int qs = 0; qs < 4; ++qs)
                    af[qs] = *reinterpret_cast<const short8*>(As + (wr * 64 + qs * 16 + (lane & 15)) * LDA + colo);
                #pragma unroll
                for (int ns = 0; ns < 4; ++ns)
                    bf[ns] = *reinterpret_cast<const short8*>(Bs + (wc * 64 + ns * 16 + (lane & 15)) * LDA + colo);
                #pragma unroll
                for (int qs = 0; qs < 4; ++qs)
                    #pragma unroll
                    for (int ns = 0; ns < 4; ++ns)
                        acc[qs][ns] = __builtin_amdgcn_mfma_f32_16x16x32_bf16(af[qs], bf[ns], acc[qs][ns], 0, 0, 0);
            }
        }

        // selection: two 64-col halves, scores spilled to LDS
        #pragma unroll 1
        for (int h = 0; h < 2; ++h) {
            __syncthreads();
            if (wc == h) {
                #pragma unroll
                for (int qs = 0; qs < 4; ++qs)
                    #pragma unroll
                    for (int ns = 0; ns < 4; ++ns)
                        #pragma unroll
                        for (int r = 0; r < 4; ++r)
                            Ss[(wr * 64 + qs * 16 + (lane >> 4) * 4 + r) * LDA + ns * 16 + (lane & 15)] = acc[qs][ns][r];
            }
            __syncthreads();
            const int q = t >> 1, part = t & 1;
            const f32x4* rowp = reinterpret_cast<const f32x4*>(Ss + q * LDA + part * 32);
            const size_t nb = nbase + h * 64 + part * 32;
            #pragma unroll
            for (int j = 0; j < 8; ++j) {
                f32x4 v = rowp[j];
                #pragma unroll
                for (int e = 0; e < 4; ++e) {
                    float x = v[e];
                    if ((nb + (size_t)(j * 4 + e)) < (size_t)NDB && x > top[TOPK - 1])
                        topk_insert(top, x);
                }
            }
        }
    }

    // block-level merge: 2 partial top-10s per query -> 10
    __syncthreads();
    {
        const int q = t >> 1, part = t & 1;
        #pragma unroll
        for (int i = 0; i < TOPK; ++i) Ms[q * 20 + part * 10 + i] = top[i];
    }
    __syncthreads();
    if (t < 128) {
        float best[TOPK];
        #pragma unroll
        for (int i = 0; i < TOPK; ++i) best[i] = -1e30f;
        for (int i = 0; i < 20; ++i) {
            float x = Ms[t * 20 + i];
            if (x > best[TOPK - 1]) topk_insert(best, x);
        }
        float* dst = partial + ((size_t)nc * NQ + qbase + t) * TOPK;
        #pragma unroll
        for (int i = 0; i < TOPK; ++i) dst[i] = best[i];
    }
}

// ---------- merge chunks, emit k-th squared distance ----------
__global__ void final_merge(const float* __restrict__ partial, float* __restrict__ out) {
    int q = blockIdx.x * 256 + threadIdx.x;
    if (q >= NQ) return;
    float top[TOPK];
    #pragma unroll
    for (int i = 0; i < TOPK; ++i) top[i] = -1e30f;
    for (int c = 0; c < NCHUNK; ++c) {
        const float* p = partial + ((size_t)c * NQ + q) * TOPK;
        #pragma unroll
        for (int i = 0; i < TOPK; ++i) {
            float x = p[i];
            if (x > top[TOPK - 1]) topk_insert(top, x);
        }
    }
    out[q] = 2.0f - 2.0f * top[TOPK - 1];
}

extern "C" void kernel_launch(void* const* d_in, const int* in_sizes, int n_in,
                              void* d_out, int out_size, void* d_ws, size_t ws_size,
                              hipStream_t stream) {
    const float* features = (const float*)d_in[0];
    const float* dbf      = (const float*)d_in[2];
    float* out = (float*)d_out;

    ushort_t* dbb = (ushort_t*)d_ws;                         // [NPAD][512] bf16   ~104.9 MB
    ushort_t* qbn = dbb + (size_t)NPAD * ND;                 // [2048][512] bf16   ~2 MB
    float* partial = (float*)(qbn + (size_t)NQ * ND);        // [NCHUNK][2048][10] ~4.1 MB

    normalize_rows<<<NDB / 4, 256, 0, stream>>>(dbf, dbb, NDB);
    normalize_rows<<<NQ / 4, 256, 0, stream>>>(features, qbn, NQ);
    knn_chunk<<<NCHUNK * QTILES, 256, 0, stream>>>(qbn, dbb, partial);
    final_merge<<<(NQ + 255) / 256, 256, 0, stream>>>(partial, out);
}